// Round 5
// baseline (100.961 us; speedup 1.0000x reference)
//
#include <hip/hip_runtime.h>

// Problem constants
#define BATCH 16
#define CIN   64
#define H_    64
#define W_    64
#define IMG   (H_ * W_)      // 4096
#define OCH   128
#define NLEAF 16
#define NGATE 15
#define PH    32
#define PW    32

// LDS layout (units: floats/ints)
//   XS:   [64 ch][6 rows][64 cols]  = 24576 floats (96 KB), row halos zeroed
//   LEAF: [128 oc][16] packed ints  =  2048 ints   (8 KB)
//   OPS:  [128 oc] x uint4 (15 op bytes + pad) = 512 uints (2 KB)
//   Z:    [6 rows][64] zeros (column-halo target) = 384 floats (1.5 KB)
#define XS_F   0
#define LEAF_F 24576
#define OPS_F  26624
#define ZF     27136
#define SMEM_F 27520          // 110080 bytes total

__device__ __constant__ __align__(16) float OP2POLY[16][4] = {
    {0, 0, 0, 0}, {0, 0, 0, 1}, {0, 1, 0, -1}, {0, 1, 0, 0},
    {0, 0, 1, -1}, {0, 0, 1, 0}, {0, 1, 1, -2}, {0, 1, 1, -1},
    {1, -1, -1, 1}, {1, -1, -1, 2}, {1, 0, -1, 0}, {1, 0, -1, 1},
    {1, -1, 0, 0}, {1, -1, 0, 1}, {1, 0, 0, -1}, {1, 0, 0, 0}};

static __device__ __forceinline__ int rfl_i(int v) {
    return __builtin_amdgcn_readfirstlane(v);
}

// Block = (b, strip of 4 pre-pool rows). 1024 threads = 16 waves.
// Phase 1: stage x[b, :, r0-1..r0+4, :] into LDS (row halo -> 0), compute
//   per-gate argmax op bytes and packed leaf descriptors into LDS.
// Phase 2: wave w handles ocs [8w, 8w+8); lane = column. Per pixel:
//   16 stride-1 ds_reads (column halo redirected to a zeroed LDS strip,
//   so no masks/branches) + 15-gate polynomial tree; 2x2 noisy-or pool.
__global__ __launch_bounds__(1024) void logic_tree_lds(
    const float* __restrict__ x,        // (B, Cin, 64, 64)
    const float* __restrict__ weights,  // (OC, 15, 16)
    const int* __restrict__ ci,         // (OC, 16)
    const int* __restrict__ px,         // (OC, 16)
    const int* __restrict__ py,         // (OC, 16)
    float* __restrict__ out)            // (B, OC, 32, 32)
{
    __shared__ float smem[SMEM_F];
    int* smem_i = (int*)smem;
    unsigned char* smem_b = (unsigned char*)smem;

    const int blk   = blockIdx.x;
    const int b     = blk >> 4;
    const int strip = blk & 15;
    const int r0    = strip << 2;       // first pre-pool row of the strip
    const int tid   = threadIdx.x;

    // ---- stage x rows r0-1 .. r0+4, all 64 channels (float4 granularity) ----
    const float4* xb4 = reinterpret_cast<const float4*>(x + (size_t)b * (CIN * IMG));
#pragma unroll
    for (int i = 0; i < 6; ++i) {
        int fidx = tid + i * 1024;           // < 6144 float4s
        int ch   = fidx / 96;                // 96 float4 per channel (6 rows x 16)
        int rem  = fidx - ch * 96;
        int row  = rem >> 4;                 // 0..5 (strip-local)
        int c4   = rem & 15;
        int gr   = r0 - 1 + row;             // global row, may be -1 or 64
        float4 val = make_float4(0.f, 0.f, 0.f, 0.f);
        if ((unsigned)gr < (unsigned)H_)
            val = xb4[((ch << 6) | gr) * 16 + c4];
        *reinterpret_cast<float4*>(&smem[ch * 384 + row * 64 + c4 * 4]) = val;
    }

    // ---- zeroed strip for column-halo lanes ----
    if (tid < 384) smem[ZF + tid] = 0.0f;

    // ---- per-gate argmax op (forward value of w is one-hot argmax) ----
    for (int t = tid; t < OCH * NGATE; t += 1024) {
        const float* wp = weights + t * 16;
        int best = 0;
        float bv = wp[0];
#pragma unroll
        for (int k = 1; k < 16; ++k) {
            float v = wp[k];
            if (v > bv) { bv = v; best = k; }    // first-max (jnp.argmax)
        }
        int oc = t / 15, g = t - oc * 15;
        smem_b[OPS_F * 4 + oc * 16 + g] = (unsigned char)best;
        if (g == 14) smem_b[OPS_F * 4 + oc * 16 + 15] = 0;
    }

    // ---- packed leaf descriptors: (ch<<4)|(py<<2)|px ----
    for (int t = tid; t < OCH * NLEAF; t += 1024)
        smem_i[LEAF_F + t] = (ci[t] << 4) | (py[t] << 2) | px[t];

    __syncthreads();

    const int wave = tid >> 6;
    const int lane = tid & 63;

#pragma unroll 1
    for (int q = 0; q < 8; ++q) {
        const int oc = wave * 8 + q;

        // gate coefficients: op bytes (uniform) -> OP2POLY rows via s_load
        const uint4 opsv =
            *reinterpret_cast<const uint4*>(&smem[OPS_F + oc * 4]);
        const unsigned ou[4] = {
            (unsigned)rfl_i((int)opsv.x), (unsigned)rfl_i((int)opsv.y),
            (unsigned)rfl_i((int)opsv.z), (unsigned)rfl_i((int)opsv.w)};
        float C[NGATE * 4];
#pragma unroll
        for (int g = 0; g < NGATE; ++g) {
            int op = (ou[g >> 2] >> ((g & 3) * 8)) & 255;
            const float4 cf = reinterpret_cast<const float4*>(OP2POLY)[op];
            C[4 * g + 0] = cf.x;
            C[4 * g + 1] = cf.y;
            C[4 * g + 2] = cf.z;
            C[4 * g + 3] = cf.w;
        }

        // leaf base addresses (float units); column halo -> zero strip
        int base[NLEAF];
#pragma unroll
        for (int n = 0; n < NLEAF; ++n) {
            int pk = rfl_i(smem_i[LEAF_F + oc * 16 + n]);
            int ch = pk >> 4;
            int dy = ((pk >> 2) & 3) - 1;
            int dx = (pk & 3) - 1;
            int c  = lane + dx;
            int ccl = min(max(c, 0), W_ - 1);
            int bin = ch * 384 + (1 + dy) * 64 + ccl;
            int bz  = ZF + (1 + dy) * 64 + lane;
            base[n] = ((unsigned)c < (unsigned)W_) ? bin : bz;
        }

        const size_t obase =
            (((size_t)b * OCH + oc) * PH + (r0 >> 1)) * PW + (lane >> 1);

        float pprev = 0.0f;
#pragma unroll
        for (int r = 0; r < 4; ++r) {
            float v[NLEAF];
#pragma unroll
            for (int n = 0; n < NLEAF; ++n)
                v[n] = smem[base[n] + r * 64];   // imm offset r*256 B

            int go = 0;
#pragma unroll
            for (int lev = 8; lev >= 1; lev >>= 1) {
#pragma unroll
                for (int t = 0; t < lev; ++t) {
                    float a  = v[2 * t];
                    float bb = v[2 * t + 1];
                    v[t] = C[(go + t) * 4] + C[(go + t) * 4 + 1] * a +
                           C[(go + t) * 4 + 2] * bb +
                           C[(go + t) * 4 + 3] * (a * bb);
                }
                go += lev;
            }

            float qv = 1.0f - v[0];
            if (r & 1) {
                float p  = pprev * qv;                 // row-pair product
                float pp = p * __shfl_xor(p, 1, 64);   // column-pair product
                if (!(lane & 1))
                    out[obase + (size_t)(r >> 1) * PW] = 1.0f - pp;
            } else {
                pprev = qv;
            }
        }
    }
}

extern "C" void kernel_launch(void* const* d_in, const int* in_sizes, int n_in,
                              void* d_out, int out_size, void* d_ws, size_t ws_size,
                              hipStream_t stream) {
    const float* x       = (const float*)d_in[0];
    const float* weights = (const float*)d_in[1];
    const int*   ci      = (const int*)d_in[2];
    const int*   px      = (const int*)d_in[3];
    const int*   py      = (const int*)d_in[4];
    float* out = (float*)d_out;
    (void)d_ws; (void)ws_size;

    logic_tree_lds<<<BATCH * 16, 1024, 0, stream>>>(x, weights, ci, px, py, out);
}

// Round 6
// 98.795 us; speedup vs baseline: 1.0219x; 1.0219x over previous
//
#include <hip/hip_runtime.h>

// Problem constants
#define BATCH 16
#define CIN   64
#define H_    64
#define W_    64
#define IMG   (H_ * W_)      // 4096
#define OCH   128
#define NLEAF 16
#define NGATE 15
#define PH    32
#define PW    32

// d_ws layout: coeffs = 128 ocs x 16 float4 (slot 15 pad) = 8192 floats,
// then packed leaf descriptors = 128 x 16 ints.
#define C_STRIDE_F4 16
#define DESC_OFF    8192
#define WS_NEED_BYTES ((DESC_OFF + OCH * NLEAF) * 4)

// LDS: XS = [64 ch][6 rows][64 cols] floats (96 KB), then 384-float zero strip
#define ZF     24576
#define SMEM_F (ZF + 384)

typedef float f2 __attribute__((ext_vector_type(2)));

__device__ __constant__ __align__(16) float OP2POLY[16][4] = {
    {0, 0, 0, 0}, {0, 0, 0, 1}, {0, 1, 0, -1}, {0, 1, 0, 0},
    {0, 0, 1, -1}, {0, 0, 1, 0}, {0, 1, 1, -2}, {0, 1, 1, -1},
    {1, -1, -1, 1}, {1, -1, -1, 2}, {1, 0, -1, 0}, {1, 0, -1, 1},
    {1, -1, 0, 0}, {1, -1, 0, 1}, {1, 0, 0, -1}, {1, 0, 0, 0}};

// ---------------------------------------------------------------------------
// Prep: coeffs[oc][g] = OP2POLY[argmax(weights[oc][g][:])] (forward value of
// w is exactly the one-hot argmax), and packed leaf descriptors
//   d = ((ch*384 + py*64) << 4) | (py << 2) | px
// ---------------------------------------------------------------------------
__global__ __launch_bounds__(1024) void prep(
    const float* __restrict__ weights,  // (OC, 15, 16)
    const int* __restrict__ ci,         // (OC, 16)
    const int* __restrict__ px,         // (OC, 16)
    const int* __restrict__ py,         // (OC, 16)
    float* __restrict__ ws)
{
    int t = blockIdx.x * 1024 + threadIdx.x;
    if (t < OCH * NGATE) {
        const float* wp = weights + t * 16;
        int best = 0;
        float bv = wp[0];
#pragma unroll
        for (int k = 1; k < 16; ++k) {
            float v = wp[k];
            if (v > bv) { bv = v; best = k; }     // first-max (jnp.argmax)
        }
        int oc = t / 15, g = t - oc * 15;
        reinterpret_cast<float4*>(ws)[oc * C_STRIDE_F4 + g] =
            reinterpret_cast<const float4*>(OP2POLY)[best];
    } else if (t < OCH * NGATE + OCH * NLEAF) {
        int t2 = t - OCH * NGATE;
        int ch = ci[t2], pyy = py[t2], pxx = px[t2];
        ((int*)ws)[DESC_OFF + t2] = ((ch * 384 + pyy * 64) << 4) | (pyy << 2) | pxx;
    }
}

// ---------------------------------------------------------------------------
// Main. Block = (b, strip of 4 pre-pool rows); 1024 threads = 16 waves;
// XCD swizzle: XCD x handles batches 2x,2x+1 (x stays L2-resident).
// Phase 1: stage x[b,:,r0-1..r0+4,:] into LDS (row halo zeroed) + zero strip.
// Phase 2: wave w -> ocs [8w,8w+8); lane = column. Per oc: coeffs + descs via
// uniform s_load (scalar pipe); per row-pair: 16 ds_read2_b32 (rows as
// .x/.y at +256 B) + packed-fp32 gate tree (v_pk_fma_f32) + 2x2 noisy-or.
// Column halo redirected to zero strip -> no masks in the hot loop.
// ---------------------------------------------------------------------------
__global__ __launch_bounds__(1024) void logic_tree_main(
    const float* __restrict__ x,        // (B, Cin, 64, 64)
    const float* __restrict__ ws,
    float* __restrict__ out)            // (B, OC, 32, 32)
{
    __shared__ float smem[SMEM_F];

    const int blk = blockIdx.x;
    const int xcd = blk & 7;
    const int j   = blk >> 3;
    const int b   = (xcd << 1) | (j >> 4);
    const int strip = j & 15;
    const int r0  = strip << 2;
    const int tid = threadIdx.x;

    // ---- stage x rows r0-1 .. r0+4, all 64 channels ----
    const float4* xb4 = reinterpret_cast<const float4*>(x + (size_t)b * (CIN * IMG));
#pragma unroll
    for (int i = 0; i < 6; ++i) {
        int fidx = tid + i * 1024;           // < 6144 float4s; LDS off = 16B*fidx
        int ch   = fidx / 96;                // 96 float4 per channel (6 rows x 16)
        int rem  = fidx - ch * 96;
        int row  = rem >> 4;
        int c4   = rem & 15;
        int gr   = r0 - 1 + row;
        float4 val = make_float4(0.f, 0.f, 0.f, 0.f);
        if ((unsigned)gr < (unsigned)H_)
            val = xb4[((ch << 6) | gr) * 16 + c4];
        *reinterpret_cast<float4*>(&smem[fidx * 4]) = val;
    }
    if (tid < 384) smem[ZF + tid] = 0.0f;
    __syncthreads();

    const int wave = tid >> 6;
    const int lane = tid & 63;

#pragma unroll 1
    for (int q = 0; q < 8; ++q) {
        const int oc = __builtin_amdgcn_readfirstlane(wave * 8 + q);
        const float4* C4 = reinterpret_cast<const float4*>(ws) + oc * C_STRIDE_F4;
        const int*    D  = ((const int*)ws) + DESC_OFF + oc * NLEAF;

        // leaf base addresses (float units); column halo -> zero strip
        int base[NLEAF];
#pragma unroll
        for (int n = 0; n < NLEAF; ++n) {
            int d  = D[n];                       // uniform -> s_load
            int c  = lane + (d & 3) - 1;
            int ccl = min(max(c, 0), W_ - 1);
            int bin = (d >> 4) + ccl;            // ch*384 + py*64 + ccl
            int bz  = ZF + ((d >> 2) & 3) * 64 + lane;
            base[n] = (c == ccl) ? bin : bz;
        }

        const size_t obase =
            (((size_t)b * OCH + oc) * PH + (strip << 1)) * PW + (lane >> 1);

#pragma unroll
        for (int rp = 0; rp < 2; ++rp) {
            f2 v[NLEAF];
#pragma unroll
            for (int n = 0; n < NLEAF; ++n) {
                v[n].x = smem[base[n] + rp * 128];        // ds_read2_b32:
                v[n].y = smem[base[n] + rp * 128 + 64];   //  rows 2rp, 2rp+1
            }
            int go = 0;
#pragma unroll
            for (int lev = 8; lev >= 1; lev >>= 1) {
#pragma unroll
                for (int t = 0; t < lev; ++t) {
                    const float4 cc = C4[go + t];         // uniform s_load
                    f2 a  = v[2 * t];
                    f2 bb = v[2 * t + 1];
                    v[t] = cc.x + cc.y * a + cc.z * bb + cc.w * (a * bb);
                }
                go += lev;
            }
            float p  = (1.0f - v[0].x) * (1.0f - v[0].y);  // row-pair product
            float pp = p * __shfl_xor(p, 1, 64);           // column-pair product
            if (!(lane & 1))
                out[obase + (size_t)rp * PW] = 1.0f - pp;
        }
    }
}

extern "C" void kernel_launch(void* const* d_in, const int* in_sizes, int n_in,
                              void* d_out, int out_size, void* d_ws, size_t ws_size,
                              hipStream_t stream) {
    const float* x       = (const float*)d_in[0];
    const float* weights = (const float*)d_in[1];
    const int*   ci      = (const int*)d_in[2];
    const int*   px      = (const int*)d_in[3];
    const int*   py      = (const int*)d_in[4];
    float* out = (float*)d_out;
    float* ws  = (float*)d_ws;   // needs 40 KB; harness provides far more

    prep<<<4, 1024, 0, stream>>>(weights, ci, px, py, ws);
    logic_tree_main<<<BATCH * 16, 1024, 0, stream>>>(x, ws, out);
}

// Round 7
// 90.761 us; speedup vs baseline: 1.1124x; 1.0885x over previous
//
#include <hip/hip_runtime.h>

// Problem constants
#define BATCH 16
#define CIN   64
#define H_    64
#define W_    64
#define IMG   (H_ * W_)      // 4096
#define OCH   128
#define NLEAF 16
#define NGATE 15
#define PH    32
#define PW    32

// d_ws: coeffs = 128 ocs x 16 float4 (slot15 pad) = 8192 floats, then descs
#define C_STRIDE_F4 16
#define DESC_OFF    8192

// LDS: 2 guard zeros, then [64 ch][6 rows][66 cols] floats; cols 64,65 = 0.
// Row stride 66 makes col -1 of row r alias row r-1's zero pad -> both
// column halos are free; no masks/clamps/cndmask in the hot loop.
#define ROWS   6
#define RSTR   66
#define CHSTR  (ROWS * RSTR)        // 396
#define XSB    2
#define SMEM_F (XSB + CIN * CHSTR)  // 25346 floats = 101,384 B

typedef float f4v __attribute__((ext_vector_type(4)));

__device__ __constant__ __align__(16) float OP2POLY[16][4] = {
    {0, 0, 0, 0}, {0, 0, 0, 1}, {0, 1, 0, -1}, {0, 1, 0, 0},
    {0, 0, 1, -1}, {0, 0, 1, 0}, {0, 1, 1, -2}, {0, 1, 1, -1},
    {1, -1, -1, 1}, {1, -1, -1, 2}, {1, 0, -1, 0}, {1, 0, -1, 1},
    {1, -1, 0, 0}, {1, -1, 0, 1}, {1, 0, 0, -1}, {1, 0, 0, 0}};

// ---------------------------------------------------------------------------
// Prep: coeffs[oc][g] = OP2POLY[argmax(weights[oc][g][:])] (forward value of
// the straight-through w is exactly the one-hot argmax), and leaf descriptors
//   desc = XSB + ch*CHSTR + py*RSTR + px - 1   (wave-uniform; s_load in main)
// ---------------------------------------------------------------------------
__global__ __launch_bounds__(1024) void prep(
    const float* __restrict__ weights,  // (OC, 15, 16)
    const int* __restrict__ ci,         // (OC, 16)
    const int* __restrict__ px,         // (OC, 16)
    const int* __restrict__ py,         // (OC, 16)
    float* __restrict__ ws)
{
    int t = blockIdx.x * 1024 + threadIdx.x;
    if (t < OCH * NGATE) {
        const float* wp = weights + t * 16;
        int best = 0;
        float bv = wp[0];
#pragma unroll
        for (int k = 1; k < 16; ++k) {
            float v = wp[k];
            if (v > bv) { bv = v; best = k; }     // first-max (jnp.argmax)
        }
        int oc = t / 15, g = t - oc * 15;
        reinterpret_cast<float4*>(ws)[oc * C_STRIDE_F4 + g] =
            reinterpret_cast<const float4*>(OP2POLY)[best];
    } else if (t < OCH * NGATE + OCH * NLEAF) {
        int t2 = t - OCH * NGATE;
        ((int*)ws)[DESC_OFF + t2] =
            XSB + ci[t2] * CHSTR + py[t2] * RSTR + px[t2] - 1;
    }
}

// ---------------------------------------------------------------------------
// Main. Block = (b, strip of 4 pre-pool rows); 1024 threads = 16 waves;
// XCD swizzle (XCD x -> batches 2x,2x+1). Phase 1: stage x rows r0-1..r0+4
// (64 ch) into stride-66 LDS with zeroed pads (free halos). Phase 2: wave w
// -> ocs [8w,8w+8); lane = column. Per oc: 16 descs via s_load, base =
// desc+lane (1 VALU), 4 rows as an f4 vector (ds_read2-pairable offsets
// 0/66/132/198), 15-gate tree in 4-wide fp32, 2x2 noisy-or pool, one
// all-lane store (even lanes row 2s, odd lanes row 2s+1).
// ---------------------------------------------------------------------------
__global__ __launch_bounds__(1024, 4) void logic_tree_main(
    const float* __restrict__ x,        // (B, Cin, 64, 64)
    const float* __restrict__ ws,
    float* __restrict__ out)            // (B, OC, 32, 32)
{
    __shared__ float smem[SMEM_F];

    const int blk = blockIdx.x;
    const int xcd = blk & 7;
    const int j   = blk >> 3;
    const int b   = (xcd << 1) | (j >> 4);
    const int strip = j & 15;
    const int r0  = strip << 2;
    const int tid = threadIdx.x;

    // ---- stage interior (float2; coalesced 512 B per wave-load) ----
    const float2* xb2 =
        reinterpret_cast<const float2*>(x + (size_t)b * (CIN * IMG));
#pragma unroll
    for (int i = 0; i < 12; ++i) {
        int f   = tid + i * 1024;        // < 12288 float2s
        int ch  = f / 192;               // 192 float2 per channel (6 rows x 32)
        int rem = f - ch * 192;
        int row = rem >> 5;
        int c2  = rem & 31;
        int gr  = r0 - 1 + row;
        float2 val = make_float2(0.f, 0.f);
        if ((unsigned)gr < (unsigned)H_)
            val = xb2[((ch << 6) | gr) * 32 + c2];
        *reinterpret_cast<float2*>(&smem[XSB + ch * CHSTR + row * RSTR + c2 * 2]) = val;
    }
    // ---- zero pads: 2 guard floats + 2 per (ch,row) ----
    if (tid < 770) {
        int idx = (tid < 768) ? (XSB + (tid >> 1) * RSTR + 64 + (tid & 1))
                              : (tid - 768);
        smem[idx] = 0.0f;
    }
    __syncthreads();

    const int wave = tid >> 6;
    const int lane = tid & 63;

#pragma unroll 1
    for (int q = 0; q < 8; ++q) {
        const int oc = __builtin_amdgcn_readfirstlane(wave * 8 + q);
        const float4* C4 = reinterpret_cast<const float4*>(ws) + oc * C_STRIDE_F4;
        const int*    D  = ((const int*)ws) + DESC_OFF + oc * NLEAF;

        // leaf rows r0..r0+3 as one f4; base = desc + lane (halos via pads)
        f4v v[NLEAF];
#pragma unroll
        for (int n = 0; n < NLEAF; ++n) {
            const int base = D[n] + lane;        // desc is SGPR (s_load)
            v[n].x = smem[base];
            v[n].y = smem[base + RSTR];
            v[n].z = smem[base + 2 * RSTR];
            v[n].w = smem[base + 3 * RSTR];
        }

        // 15-gate polynomial tree, 4 rows wide
        int go = 0;
#pragma unroll
        for (int lev = 8; lev >= 1; lev >>= 1) {
#pragma unroll
            for (int t = 0; t < lev; ++t) {
                const float4 cc = C4[go + t];    // uniform s_load
                f4v a  = v[2 * t];
                f4v bb = v[2 * t + 1];
                v[t] = cc.x + cc.y * a + cc.z * bb + cc.w * (a * bb);
            }
            go += lev;
        }

        // 2x2 noisy-or pool; even lanes -> pooled row 2*strip, odd -> +1
        float p0 = (1.0f - v[0].x) * (1.0f - v[0].y);
        float p1 = (1.0f - v[0].z) * (1.0f - v[0].w);
        float q0 = p0 * __shfl_xor(p0, 1, 64);
        float q1 = p1 * __shfl_xor(p1, 1, 64);
        float val = (lane & 1) ? (1.0f - q1) : (1.0f - q0);
        out[(((size_t)b * OCH + oc) * PH + (strip << 1) + (lane & 1)) * PW +
            (lane >> 1)] = val;
    }
}

extern "C" void kernel_launch(void* const* d_in, const int* in_sizes, int n_in,
                              void* d_out, int out_size, void* d_ws, size_t ws_size,
                              hipStream_t stream) {
    const float* x       = (const float*)d_in[0];
    const float* weights = (const float*)d_in[1];
    const int*   ci      = (const int*)d_in[2];
    const int*   px      = (const int*)d_in[3];
    const int*   py      = (const int*)d_in[4];
    float* out = (float*)d_out;
    float* ws  = (float*)d_ws;   // needs 40 KB

    prep<<<4, 1024, 0, stream>>>(weights, ci, px, py, ws);
    logic_tree_main<<<BATCH * 16, 1024, 0, stream>>>(x, ws, out);
}